// Round 1
// baseline (2314.558 us; speedup 1.0000x reference)
//
#include <hip/hip_runtime.h>
#include <hip/hip_bf16.h>
#include <stdint.h>

// ---------------- problem constants ----------------
#define NTOK   8192      // 2*4096 tokens
#define DMODEL 2048
#define FFN    2048
#define NEXP   16
#define TOPK   4

#define BM 128
#define BK 64
#define MAXTILES (NEXP + (NTOK*TOPK)/BM)   // 272 worst-case M-tiles over all experts

typedef __attribute__((ext_vector_type(4))) float    f32x4;
typedef __attribute__((ext_vector_type(4))) _Float16 f16x4;
typedef __attribute__((ext_vector_type(8))) _Float16 f16x8;

typedef __attribute__((address_space(1))) void gvoid;
typedef __attribute__((address_space(3))) void lvoid;
// direct global->LDS, 16B per lane, dest = wave-uniform base + lane*16
#define GLDS16(gp, lp) __builtin_amdgcn_global_load_lds((gvoid*)(gp), (lvoid*)(lp), 16, 0, 0)

// ---------------- prep kernels ----------------

__global__ void k_sentinel(float* o){ o[0] = 3.0e7f; }   // ws too small marker

__global__ void k_convert_x(const float* __restrict__ x, _Float16* __restrict__ xh){
  const size_t n8 = (size_t)NTOK * DMODEL / 8;
  for (size_t i = (size_t)blockIdx.x * blockDim.x + threadIdx.x; i < n8;
       i += (size_t)gridDim.x * blockDim.x){
    const float4* p = (const float4*)(x + i*8);
    float4 v0 = p[0], v1 = p[1];
    f16x8 o;
    o[0]=(_Float16)v0.x; o[1]=(_Float16)v0.y; o[2]=(_Float16)v0.z; o[3]=(_Float16)v0.w;
    o[4]=(_Float16)v1.x; o[5]=(_Float16)v1.y; o[6]=(_Float16)v1.z; o[7]=(_Float16)v1.w;
    *(f16x8*)(xh + i*8) = o;
  }
}

// transpose one 2048x2048 fp32 matrix per blockIdx.z into fp16 (dst[c][r] = src[r][c])
__global__ void k_transpose(const float* __restrict__ src, _Float16* __restrict__ dst){
  __shared__ float t[32][33];
  const size_t mo = (size_t)blockIdx.z * DMODEL * FFN;
  const float* S = src + mo;
  _Float16*    D = dst + mo;
  const int tx = threadIdx.x, ty = threadIdx.y;           // 32 x 8
  const int x0 = blockIdx.x * 32, y0 = blockIdx.y * 32;
#pragma unroll
  for (int i = 0; i < 4; ++i)
    t[ty + 8*i][tx] = S[(size_t)(y0 + ty + 8*i) * 2048 + (x0 + tx)];
  __syncthreads();
#pragma unroll
  for (int i = 0; i < 4; ++i)
    D[(size_t)(x0 + ty + 8*i) * 2048 + (y0 + tx)] = (_Float16)t[tx][ty + 8*i];
}

// ---------------- router: logits -> softmax -> top4 -> L1-normalized weights ----------------
__global__ __launch_bounds__(64) void k_router(const float* __restrict__ x,
                                               const float* __restrict__ wr,
                                               int*   __restrict__ counts,
                                               int*   __restrict__ ids,
                                               float* __restrict__ wts){
  const int t = blockIdx.x, lane = threadIdx.x;
  const float* xr = x + (size_t)t * DMODEL;
  float acc[NEXP];
#pragma unroll
  for (int e = 0; e < NEXP; ++e) acc[e] = 0.f;
  for (int d = lane; d < DMODEL; d += 64){
    float xv = xr[d];
#pragma unroll
    for (int e = 0; e < NEXP; ++e) acc[e] += xv * wr[e*DMODEL + d];
  }
#pragma unroll
  for (int e = 0; e < NEXP; ++e){
    float v = acc[e];
#pragma unroll
    for (int s = 32; s > 0; s >>= 1) v += __shfl_xor(v, s);
    acc[e] = v;
  }
  if (lane == 0){
    int mask = 0; float tv[TOPK]; int te[TOPK];
    for (int k = 0; k < TOPK; ++k){           // strict '>' keeps lowest index on ties (matches lax.top_k)
      float best = -3.0e38f; int bi = 0;
      for (int e = 0; e < NEXP; ++e)
        if (!((mask >> e) & 1) && acc[e] > best){ best = acc[e]; bi = e; }
      mask |= 1 << bi; tv[k] = best; te[k] = bi;
    }
    // softmax over all then renorm over top4  ==  exp(l-max)/sum_top4 exp(l-max)
    float m = tv[0], s = 0.f, w[TOPK];
    for (int k = 0; k < TOPK; ++k){ w[k] = __expf(tv[k] - m); s += w[k]; }
    float inv = 1.f / s;
    for (int k = 0; k < TOPK; ++k){
      int slot = atomicAdd(&counts[te[k]], 1);
      ids[te[k]*NTOK + slot] = t;
      wts[te[k]*NTOK + slot] = w[k] * inv;
    }
  }
}

// ---------------- grouped GEMM 1: H = silu(X@Wg) * (X@Wu), fp16 in/out, fp32 acc ----------------
// tile 128(M) x 64(N), BK=64, 4 waves (wave tile 64x32), both operands K-contiguous (wgT/wuT pre-transposed)
__global__ __launch_bounds__(256, 2) void k_gateup(
    const _Float16* __restrict__ xh,
    const _Float16* __restrict__ wgT,   // [NEXP][FFN][DMODEL]
    const _Float16* __restrict__ wuT,
    const int* __restrict__ counts,
    const int* __restrict__ ids,
    _Float16* __restrict__ H)
{
  __shared__ __align__(16) char smem[32*1024];
  char* ldsA  = smem;               // [128][128B] swizzled
  char* ldsBg = smem + 16*1024;     // [64][128B]
  char* ldsBu = smem + 24*1024;

  int e = -1, mt = 0, rowbase = 0;
  {
    int at = 0, rb = 0;
#pragma unroll
    for (int i = 0; i < NEXP; ++i){
      int c = counts[i];
      int nt = (c + BM - 1) >> 7;
      if (e < 0 && (int)blockIdx.x < at + nt){ e = i; mt = (int)blockIdx.x - at; rowbase = rb; }
      at += nt; rb += nt * BM;
    }
  }
  if (e < 0) return;

  const int tid = threadIdx.x, lane = tid & 63, w = tid >> 6;
  const int n0 = blockIdx.y * 64;
  const int l8 = lane >> 3, c_ = lane & 7;

  // staging source pointers (per lane); source chunk permuted by (row&7) -> XOR-swizzled LDS
  const char* aptr[4];
#pragma unroll
  for (int q = 0; q < 4; ++q){
    int r = (w + 4*q)*8 + l8;
    int tok = ids[e*NTOK + mt*BM + r];
    int c = c_ ^ (r & 7);
    aptr[q] = (const char*)(xh + (size_t)tok * DMODEL) + c*16;
  }
  const char* bgptr[2]; const char* buptr[2];
#pragma unroll
  for (int q = 0; q < 2; ++q){
    int rn = (w + 4*q)*8 + l8;
    int c = c_ ^ (rn & 7);
    size_t row = (size_t)e * FFN + (n0 + rn);
    bgptr[q] = (const char*)(wgT + row * DMODEL) + c*16;
    buptr[q] = (const char*)(wuT + row * DMODEL) + c*16;
  }

  f32x4 ag[4][2], au[4][2];
#pragma unroll
  for (int m = 0; m < 4; ++m)
#pragma unroll
    for (int n = 0; n < 2; ++n){ ag[m][n] = (f32x4)(0.0f); au[m][n] = (f32x4)(0.0f); }

  const int wm = w >> 1, wn = w & 1, hi = lane >> 4;

  for (int ks = 0; ks < DMODEL/BK; ++ks){
    const int kb = ks * (BK*2);
    __syncthreads();
#pragma unroll
    for (int q = 0; q < 4; ++q) GLDS16(aptr[q] + kb, ldsA + (w + 4*q)*1024);
#pragma unroll
    for (int q = 0; q < 2; ++q){
      GLDS16(bgptr[q] + kb, ldsBg + (w + 4*q)*1024);
      GLDS16(buptr[q] + kb, ldsBu + (w + 4*q)*1024);
    }
    __syncthreads();
#pragma unroll
    for (int ksub = 0; ksub < 2; ++ksub){
      f16x8 af[4];
#pragma unroll
      for (int m = 0; m < 4; ++m){
        int r = wm*64 + m*16 + (lane & 15);
        int X = (r & 7) << 4;
        f16x4 a0 = *(const f16x4*)(ldsA + r*128 + ((ksub*64 + hi*8     ) ^ X));
        f16x4 a1 = *(const f16x4*)(ldsA + r*128 + ((ksub*64 + hi*8 + 32) ^ X));
        af[m] = __builtin_shufflevector(a0, a1, 0,1,2,3,4,5,6,7);
      }
#pragma unroll
      for (int n = 0; n < 2; ++n){
        int r = wn*32 + n*16 + (lane & 15);
        int X = (r & 7) << 4;
        f16x4 g0 = *(const f16x4*)(ldsBg + r*128 + ((ksub*64 + hi*8     ) ^ X));
        f16x4 g1 = *(const f16x4*)(ldsBg + r*128 + ((ksub*64 + hi*8 + 32) ^ X));
        f16x8 bg = __builtin_shufflevector(g0, g1, 0,1,2,3,4,5,6,7);
        f16x4 u0 = *(const f16x4*)(ldsBu + r*128 + ((ksub*64 + hi*8     ) ^ X));
        f16x4 u1 = *(const f16x4*)(ldsBu + r*128 + ((ksub*64 + hi*8 + 32) ^ X));
        f16x8 bu = __builtin_shufflevector(u0, u1, 0,1,2,3,4,5,6,7);
#pragma unroll
        for (int m = 0; m < 4; ++m){
          ag[m][n] = __builtin_amdgcn_mfma_f32_16x16x32_f16(af[m], bg, ag[m][n], 0, 0, 0);
          au[m][n] = __builtin_amdgcn_mfma_f32_16x16x32_f16(af[m], bu, au[m][n], 0, 0, 0);
        }
      }
    }
  }

  // epilogue: silu(g)*u -> H (C/D: col = lane&15, row = (lane>>4)*4 + j)
  const int hrow0 = rowbase + mt*BM + wm*64;
#pragma unroll
  for (int m = 0; m < 4; ++m){
#pragma unroll
    for (int n = 0; n < 2; ++n){
      f32x4 g = ag[m][n], u = au[m][n];
#pragma unroll
      for (int j = 0; j < 4; ++j){
        int row = hrow0 + m*16 + hi*4 + j;
        int col = n0 + wn*32 + n*16 + (lane & 15);
        float gv = g[j], uv = u[j];
        float hv = gv / (1.f + __expf(-gv)) * uv;
        H[(size_t)row * FFN + col] = (_Float16)hv;
      }
    }
  }
}

// ---------------- grouped GEMM 2: out += w * (H @ Wd), atomic combine ----------------
// tile 128 x 128, BK=64, 4 waves (wave tile 64x64)
__global__ __launch_bounds__(256, 2) void k_down(
    const _Float16* __restrict__ H,
    const _Float16* __restrict__ wdT,   // [NEXP][DMODEL][FFN]
    const int* __restrict__ counts,
    const int* __restrict__ ids,
    const float* __restrict__ wts,
    float* __restrict__ out)
{
  __shared__ __align__(16) char smem[32*1024];
  char* ldsA = smem;               // [128][128B]
  char* ldsB = smem + 16*1024;     // [128][128B]

  int e = -1, mt = 0, rowbase = 0;
  {
    int at = 0, rb = 0;
#pragma unroll
    for (int i = 0; i < NEXP; ++i){
      int c = counts[i];
      int nt = (c + BM - 1) >> 7;
      if (e < 0 && (int)blockIdx.x < at + nt){ e = i; mt = (int)blockIdx.x - at; rowbase = rb; }
      at += nt; rb += nt * BM;
    }
  }
  if (e < 0) return;

  const int tid = threadIdx.x, lane = tid & 63, w = tid >> 6;
  const int n0 = blockIdx.y * 128;
  const int l8 = lane >> 3, c_ = lane & 7;

  const char* aptr[4]; const char* bptr[4];
#pragma unroll
  for (int q = 0; q < 4; ++q){
    int r = (w + 4*q)*8 + l8;
    int c = c_ ^ (r & 7);
    aptr[q] = (const char*)(H   + (size_t)(rowbase + mt*BM + r) * FFN) + c*16;
    bptr[q] = (const char*)(wdT + ((size_t)e * DMODEL + (n0 + r)) * FFN) + c*16;
  }

  f32x4 acc[4][4];
#pragma unroll
  for (int m = 0; m < 4; ++m)
#pragma unroll
    for (int n = 0; n < 4; ++n) acc[m][n] = (f32x4)(0.0f);

  const int wm = w >> 1, wn = w & 1, hi = lane >> 4;

  for (int ks = 0; ks < FFN/BK; ++ks){
    const int kb = ks * (BK*2);
    __syncthreads();
#pragma unroll
    for (int q = 0; q < 4; ++q){
      GLDS16(aptr[q] + kb, ldsA + (w + 4*q)*1024);
      GLDS16(bptr[q] + kb, ldsB + (w + 4*q)*1024);
    }
    __syncthreads();
#pragma unroll
    for (int ksub = 0; ksub < 2; ++ksub){
      f16x8 af[4], bf[4];
#pragma unroll
      for (int m = 0; m < 4; ++m){
        int r = wm*64 + m*16 + (lane & 15);
        int X = (r & 7) << 4;
        f16x4 a0 = *(const f16x4*)(ldsA + r*128 + ((ksub*64 + hi*8     ) ^ X));
        f16x4 a1 = *(const f16x4*)(ldsA + r*128 + ((ksub*64 + hi*8 + 32) ^ X));
        af[m] = __builtin_shufflevector(a0, a1, 0,1,2,3,4,5,6,7);
      }
#pragma unroll
      for (int n = 0; n < 4; ++n){
        int r = wn*64 + n*16 + (lane & 15);
        int X = (r & 7) << 4;
        f16x4 b0 = *(const f16x4*)(ldsB + r*128 + ((ksub*64 + hi*8     ) ^ X));
        f16x4 b1 = *(const f16x4*)(ldsB + r*128 + ((ksub*64 + hi*8 + 32) ^ X));
        bf[n] = __builtin_shufflevector(b0, b1, 0,1,2,3,4,5,6,7);
      }
#pragma unroll
      for (int m = 0; m < 4; ++m)
#pragma unroll
        for (int n = 0; n < 4; ++n)
          acc[m][n] = __builtin_amdgcn_mfma_f32_16x16x32_f16(af[m], bf[n], acc[m][n], 0, 0, 0);
    }
  }

#pragma unroll
  for (int m = 0; m < 4; ++m){
#pragma unroll
    for (int j = 0; j < 4; ++j){
      int li = mt*BM + wm*64 + m*16 + hi*4 + j;
      int t  = ids[e*NTOK + li];
      float wv = wts[e*NTOK + li];          // padding rows: t=0, wv=0 -> adds 0
      float* orow = out + (size_t)t * DMODEL;
#pragma unroll
      for (int n = 0; n < 4; ++n){
        int col = n0 + wn*64 + n*16 + (lane & 15);
        atomicAdd(&orow[col], wv * acc[m][n][j]);
      }
    }
  }
}

// ---------------- host launch ----------------
extern "C" void kernel_launch(void* const* d_in, const int* in_sizes, int n_in,
                              void* d_out, int out_size, void* d_ws, size_t ws_size,
                              hipStream_t stream)
{
  const float* x  = (const float*)d_in[0];
  const float* wr = (const float*)d_in[1];
  const float* wg = (const float*)d_in[2];
  const float* wu = (const float*)d_in[3];
  const float* wd = (const float*)d_in[4];
  float* out = (float*)d_out;
  char* ws = (char*)d_ws;

  const size_t OFF_IDS = 256;
  const size_t OFF_WTS = OFF_IDS + (size_t)NEXP*NTOK*4;
  const size_t OFF_XH  = OFF_WTS + (size_t)NEXP*NTOK*4;
  const size_t OFF_WT  = OFF_XH  + (size_t)NTOK*DMODEL*2;
  const size_t OFF_H   = OFF_WT  + 2*(size_t)NEXP*DMODEL*FFN*2;
  const size_t HROWS   = (size_t)NTOK*TOPK + NEXP*BM;     // 34816 incl. padding
  const size_t NEED    = OFF_H + HROWS*FFN*2;
  if (ws_size < NEED){ k_sentinel<<<1,1,0,stream>>>(out); return; }

  int*      counts = (int*)ws;
  int*      ids    = (int*)(ws + OFF_IDS);
  float*    wts    = (float*)(ws + OFF_WTS);
  _Float16* xh     = (_Float16*)(ws + OFF_XH);
  _Float16* wgT    = (_Float16*)(ws + OFF_WT);
  _Float16* wuT    = wgT + (size_t)NEXP*DMODEL*FFN;
  _Float16* wdT    = wgT;                   // alias: used only after k_gateup finished
  _Float16* H      = (_Float16*)(ws + OFF_H);

  hipMemsetAsync(out, 0, (size_t)out_size * sizeof(float), stream);
  hipMemsetAsync(ws, 0, OFF_XH, stream);    // counts + ids + wts (zeros => padding weight 0, token 0)

  k_convert_x<<<1024, 256, 0, stream>>>(x, xh);
  dim3 tb(32, 8);
  k_transpose<<<dim3(64,64,16), tb, 0, stream>>>(wg, wgT);
  k_transpose<<<dim3(64,64,16), tb, 0, stream>>>(wu, wuT);
  k_router<<<NTOK, 64, 0, stream>>>(x, wr, counts, ids, wts);
  k_gateup<<<dim3(MAXTILES, FFN/64), 256, 0, stream>>>(xh, wgT, wuT, counts, ids, H);
  k_transpose<<<dim3(64,64,16), tb, 0, stream>>>(wd, wdT);
  k_down<<<dim3(MAXTILES, DMODEL/128), 256, 0, stream>>>(H, wdT, counts, ids, wts, out);
}

// Round 2
// 1784.673 us; speedup vs baseline: 1.2969x; 1.2969x over previous
//
#include <hip/hip_runtime.h>
#include <hip/hip_bf16.h>
#include <stdint.h>

// ---------------- problem constants ----------------
#define NTOK   8192
#define DMODEL 2048
#define FFN    2048
#define NEXP   16
#define TOPK   4
#define STRIDE (NTOK + 256)                 // per-expert ids/wts stride (padding safety)

#define BM 256
#define BK 64
#define NKT (DMODEL/BK)                     // 32 K-tiles
#define MAXT ((NTOK*TOPK)/BM + NEXP)        // 144 worst-case M-tiles

typedef __attribute__((ext_vector_type(4))) float    f32x4;
typedef __attribute__((ext_vector_type(4))) _Float16 f16x4;
typedef __attribute__((ext_vector_type(8))) _Float16 f16x8;

typedef __attribute__((address_space(1))) void gvoid;
typedef __attribute__((address_space(3))) void lvoid;
#define GLDS16(gp, lp) __builtin_amdgcn_global_load_lds((gvoid*)(gp), (lvoid*)(lp), 16, 0, 0)

#define MFMA16(a,b,c) __builtin_amdgcn_mfma_f32_16x16x32_f16((a),(b),(c),0,0,0)

// ---------------- prep kernels ----------------

__global__ void k_sentinel(float* o){ o[0] = 3.0e7f; }

// transpose one 2048x2048 fp32 per blockIdx.z into fp16 (dst[c][r] = src[r][c])
__global__ void k_transpose(const float* __restrict__ src, _Float16* __restrict__ dst){
  __shared__ float t[32][33];
  const size_t mo = (size_t)blockIdx.z * DMODEL * FFN;
  const float* S = src + mo;
  _Float16*    D = dst + mo;
  const int tx = threadIdx.x, ty = threadIdx.y;  // 32 x 8
  const int x0 = blockIdx.x * 32, y0 = blockIdx.y * 32;
#pragma unroll
  for (int i = 0; i < 4; ++i)
    t[ty + 8*i][tx] = S[(size_t)(y0 + ty + 8*i) * 2048 + (x0 + tx)];
  __syncthreads();
#pragma unroll
  for (int i = 0; i < 4; ++i)
    D[(size_t)(x0 + ty + 8*i) * 2048 + (y0 + tx)] = (_Float16)t[tx][ty + 8*i];
}

// ---------------- router (fused with x -> fp16 convert) ----------------
__global__ __launch_bounds__(64) void k_router(const float* __restrict__ x,
                                               const float* __restrict__ wr,
                                               int*   __restrict__ counts,
                                               int*   __restrict__ ids,
                                               float* __restrict__ wts,
                                               _Float16* __restrict__ xh){
  const int t = blockIdx.x, lane = threadIdx.x;
  const float4* x4 = (const float4*)(x + (size_t)t * DMODEL);
  const float4* w4 = (const float4*)wr;
  float acc[NEXP];
#pragma unroll
  for (int e = 0; e < NEXP; ++e) acc[e] = 0.f;
#pragma unroll
  for (int i = 0; i < 8; ++i){
    int d4 = lane + i*64;
    float4 xv = x4[d4];
    f16x4 h; h[0]=(_Float16)xv.x; h[1]=(_Float16)xv.y; h[2]=(_Float16)xv.z; h[3]=(_Float16)xv.w;
    *(f16x4*)(xh + (size_t)t*DMODEL + d4*4) = h;
#pragma unroll
    for (int e = 0; e < NEXP; ++e){
      float4 wv = w4[e*512 + d4];
      acc[e] += xv.x*wv.x + xv.y*wv.y + xv.z*wv.z + xv.w*wv.w;
    }
  }
#pragma unroll
  for (int e = 0; e < NEXP; ++e){
    float v = acc[e];
#pragma unroll
    for (int s = 32; s > 0; s >>= 1) v += __shfl_xor(v, s);
    acc[e] = v;
  }
  if (lane == 0){
    int mask = 0; float tv[TOPK]; int te[TOPK];
    for (int k = 0; k < TOPK; ++k){      // strict '>' keeps lowest index on ties
      float best = -3.0e38f; int bi = 0;
      for (int e = 0; e < NEXP; ++e)
        if (!((mask >> e) & 1) && acc[e] > best){ best = acc[e]; bi = e; }
      mask |= 1 << bi; tv[k] = best; te[k] = bi;
    }
    float m = tv[0], s = 0.f, w[TOPK];
    for (int k = 0; k < TOPK; ++k){ w[k] = __expf(tv[k] - m); s += w[k]; }
    float inv = 1.f / s;
    for (int k = 0; k < TOPK; ++k){
      int slot = atomicAdd(&counts[te[k]], 1);
      ids[te[k]*STRIDE + slot] = t;
      wts[te[k]*STRIDE + slot] = w[k] * inv;
    }
  }
}

// ================= grouped GEMM 1: H = silu(X@Wg)*(X@Wu) =================
// 256x256 tile (256 B-rows = 128 H-cols x {gate,up}), BK=64, 8 waves (2Mx4N),
// dbuf LDS 128KB, counted-vmcnt half-tile pipeline, swizzled ds_read_b128.
__global__ __launch_bounds__(512, 2) void k_gateup(
    const _Float16* __restrict__ xh,
    const _Float16* __restrict__ wgT,   // [E][F][D]  (K=D contiguous)
    const _Float16* __restrict__ wuT,
    const int* __restrict__ counts,
    const int* __restrict__ ids,
    _Float16* __restrict__ H)
{
  __shared__ __align__(128) char smem[131072];
  char* ldsA = smem;            // [2 buf][2 half][256 rows][64 B]
  char* ldsB = smem + 65536;

  int e = -1, mt = 0, rowbase = 0;
  { int at = 0, rb = 0;
    for (int i = 0; i < NEXP; ++i){
      int c = counts[i]; int nt = (c + 255) >> 8;
      if (e < 0 && (int)blockIdx.x < at + nt){ e = i; mt = (int)blockIdx.x - at; rowbase = rb; }
      at += nt; rb += nt * BM;
    } }
  if (e < 0) return;

  const int tid = threadIdx.x, lane = tid & 63, w = tid >> 6;
  const int wm = w >> 2, wn = w & 3, hi = lane >> 4, l15 = lane & 15;
  const int n0 = blockIdx.y * 128;
  const int wdst = w * 1024;

  // staging sources: thread stages rows r = (tid>>2)+128j, 16B chunk s=tid&3,
  // source chunk pre-swizzled by (r&3) so linear LDS dest == swizzled layout.
  const int jr = tid >> 2, s4 = tid & 3;
  const char* srcA[2]; const char* srcB[2];
#pragma unroll
  for (int j = 0; j < 2; ++j){
    int r = jr + 128*j;
    int tok = ids[e*STRIDE + mt*BM + r];
    srcA[j] = (const char*)(xh + (size_t)tok * DMODEL) + ((s4 ^ (r & 3)) << 4);
    int which = (r >> 5) & 1, col = n0 + ((r >> 6) << 5) + (r & 31);
    const _Float16* Wm = which ? wuT : wgT;
    srcB[j] = (const char*)(Wm + ((size_t)e * FFN + col) * (size_t)DMODEL) + ((s4 ^ (r & 3)) << 4);
  }

  // LDS frag offsets within a half-region: r*64 + ((hi*16) ^ ((r&3)<<4))
  int aoff[8], boff[4];
#pragma unroll
  for (int m = 0; m < 8; ++m){ int r = wm*128 + m*16 + l15; aoff[m] = r*64 + ((hi<<4) ^ ((r&3)<<4)); }
#pragma unroll
  for (int n = 0; n < 4; ++n){ int r = wn*64  + n*16 + l15; boff[n] = r*64 + ((hi<<4) ^ ((r&3)<<4)); }

  f32x4 acc[8][4];
#pragma unroll
  for (int m = 0; m < 8; ++m)
#pragma unroll
    for (int n = 0; n < 4; ++n) acc[m][n] = (f32x4)(0.0f);

#define STG_A(t,h,b) { _Pragma("unroll") for (int j = 0; j < 2; ++j) \
    GLDS16(srcA[j] + (t)*128 + (h)*64, ldsA + (b)*32768 + (h)*16384 + j*8192 + wdst); }
#define STG_B(t,h,b) { _Pragma("unroll") for (int j = 0; j < 2; ++j) \
    GLDS16(srcB[j] + (t)*128 + (h)*64, ldsB + (b)*32768 + (h)*16384 + j*8192 + wdst); }

  // prologue: tile 0, issue order Ak0,Bk0,Ak1,Bk1 (FIFO basis for counted vmcnt)
  STG_A(0,0,0); STG_B(0,0,0); STG_A(0,1,0); STG_B(0,1,0);

  f16x8 af[4], bf[4];
  for (int t = 0; t < NKT; ++t){
    const int p = t & 1, b2 = p ^ 1;
    const bool stg = (t + 1 < NKT);
    const char* baseA = ldsA + p*32768;
    const char* baseB = ldsB + p*32768;
    // ---- phase 0: ksub0, m0-3 (Ak0,Bk0 must have landed: retire oldest 2 half-tiles) ----
    asm volatile("s_waitcnt vmcnt(4)" ::: "memory");
    __builtin_amdgcn_s_barrier();
    asm volatile("" ::: "memory");
#pragma unroll
    for (int n = 0; n < 4; ++n) bf[n] = *(const f16x8*)(baseB + boff[n]);
#pragma unroll
    for (int m = 0; m < 4; ++m) af[m] = *(const f16x8*)(baseA + aoff[m]);
    if (stg) STG_A(t+1, 0, b2);
    __builtin_amdgcn_s_setprio(1);
#pragma unroll
    for (int m = 0; m < 4; ++m)
#pragma unroll
      for (int n = 0; n < 4; ++n) acc[m][n] = MFMA16(af[m], bf[n], acc[m][n]);
    __builtin_amdgcn_s_setprio(0);
    // ---- phase 1: ksub0, m4-7 ----
#pragma unroll
    for (int m = 0; m < 4; ++m) af[m] = *(const f16x8*)(baseA + aoff[m+4]);
    if (stg) STG_B(t+1, 0, b2);
    __builtin_amdgcn_s_setprio(1);
#pragma unroll
    for (int m = 0; m < 4; ++m)
#pragma unroll
      for (int n = 0; n < 4; ++n) acc[m+4][n] = MFMA16(af[m], bf[n], acc[m+4][n]);
    __builtin_amdgcn_s_setprio(0);
    // ---- phase 2: ksub1, m0-3 (Ak1,Bk1 must have landed) ----
    if (stg) { asm volatile("s_waitcnt vmcnt(4)" ::: "memory"); }
    else     { asm volatile("s_waitcnt vmcnt(0)" ::: "memory"); }
    __builtin_amdgcn_s_barrier();
    asm volatile("" ::: "memory");
#pragma unroll
    for (int n = 0; n < 4; ++n) bf[n] = *(const f16x8*)(baseB + 16384 + boff[n]);
#pragma unroll
    for (int m = 0; m < 4; ++m) af[m] = *(const f16x8*)(baseA + 16384 + aoff[m]);
    if (stg) STG_A(t+1, 1, b2);
    __builtin_amdgcn_s_setprio(1);
#pragma unroll
    for (int m = 0; m < 4; ++m)
#pragma unroll
      for (int n = 0; n < 4; ++n) acc[m][n] = MFMA16(af[m], bf[n], acc[m][n]);
    __builtin_amdgcn_s_setprio(0);
    // ---- phase 3: ksub1, m4-7 ----
#pragma unroll
    for (int m = 0; m < 4; ++m) af[m] = *(const f16x8*)(baseA + 16384 + aoff[m+4]);
    if (stg) STG_B(t+1, 1, b2);
    __builtin_amdgcn_s_setprio(1);
#pragma unroll
    for (int m = 0; m < 4; ++m)
#pragma unroll
      for (int n = 0; n < 4; ++n) acc[m+4][n] = MFMA16(af[m], bf[n], acc[m+4][n]);
    __builtin_amdgcn_s_setprio(0);
  }

  // epilogue: h = silu(gate)*up ; acc[m][0,1]=gate cols, acc[m][2,3]=up cols
  const int hrow0 = rowbase + mt*BM + wm*128;
#pragma unroll
  for (int m = 0; m < 8; ++m){
#pragma unroll
    for (int nf = 0; nf < 2; ++nf){
#pragma unroll
      for (int j = 0; j < 4; ++j){
        int row = hrow0 + m*16 + hi*4 + j;
        int col = n0 + wn*32 + nf*16 + l15;
        float g = acc[m][nf][j], u = acc[m][nf+2][j];
        H[(size_t)row * FFN + col] = (_Float16)(g / (1.f + __expf(-g)) * u);
      }
    }
  }
#undef STG_A
#undef STG_B
}

// ================= grouped GEMM 2: out += w * (H @ Wd) =================
__global__ __launch_bounds__(512, 2) void k_down(
    const _Float16* __restrict__ H,
    const _Float16* __restrict__ wdT,   // [E][D][F]  (K=F contiguous)
    const int* __restrict__ counts,
    const int* __restrict__ ids,
    const float* __restrict__ wts,
    float* __restrict__ out)
{
  __shared__ __align__(128) char smem[131072];
  char* ldsA = smem;
  char* ldsB = smem + 65536;

  int e = -1, mt = 0, rowbase = 0, cnt = 0;
  { int at = 0, rb = 0;
    for (int i = 0; i < NEXP; ++i){
      int c = counts[i]; int nt = (c + 255) >> 8;
      if (e < 0 && (int)blockIdx.x < at + nt){ e = i; mt = (int)blockIdx.x - at; rowbase = rb; cnt = c; }
      at += nt; rb += nt * BM;
    } }
  if (e < 0) return;

  const int tid = threadIdx.x, lane = tid & 63, w = tid >> 6;
  const int wm = w >> 2, wn = w & 3, hi = lane >> 4, l15 = lane & 15;
  const int n0 = blockIdx.y * 256;
  const int wdst = w * 1024;

  const int jr = tid >> 2, s4 = tid & 3;
  const char* srcA[2]; const char* srcB[2];
#pragma unroll
  for (int j = 0; j < 2; ++j){
    int r = jr + 128*j;
    srcA[j] = (const char*)(H   + (size_t)(rowbase + mt*BM + r) * FFN) + ((s4 ^ (r & 3)) << 4);
    srcB[j] = (const char*)(wdT + ((size_t)e * DMODEL + n0 + r) * (size_t)FFN) + ((s4 ^ (r & 3)) << 4);
  }

  int aoff[8], boff[4];
#pragma unroll
  for (int m = 0; m < 8; ++m){ int r = wm*128 + m*16 + l15; aoff[m] = r*64 + ((hi<<4) ^ ((r&3)<<4)); }
#pragma unroll
  for (int n = 0; n < 4; ++n){ int r = wn*64  + n*16 + l15; boff[n] = r*64 + ((hi<<4) ^ ((r&3)<<4)); }

  f32x4 acc[8][4];
#pragma unroll
  for (int m = 0; m < 8; ++m)
#pragma unroll
    for (int n = 0; n < 4; ++n) acc[m][n] = (f32x4)(0.0f);

#define STG_A(t,h,b) { _Pragma("unroll") for (int j = 0; j < 2; ++j) \
    GLDS16(srcA[j] + (t)*128 + (h)*64, ldsA + (b)*32768 + (h)*16384 + j*8192 + wdst); }
#define STG_B(t,h,b) { _Pragma("unroll") for (int j = 0; j < 2; ++j) \
    GLDS16(srcB[j] + (t)*128 + (h)*64, ldsB + (b)*32768 + (h)*16384 + j*8192 + wdst); }

  STG_A(0,0,0); STG_B(0,0,0); STG_A(0,1,0); STG_B(0,1,0);

  f16x8 af[4], bf[4];
  for (int t = 0; t < NKT; ++t){
    const int p = t & 1, b2 = p ^ 1;
    const bool stg = (t + 1 < NKT);
    const char* baseA = ldsA + p*32768;
    const char* baseB = ldsB + p*32768;
    asm volatile("s_waitcnt vmcnt(4)" ::: "memory");
    __builtin_amdgcn_s_barrier();
    asm volatile("" ::: "memory");
#pragma unroll
    for (int n = 0; n < 4; ++n) bf[n] = *(const f16x8*)(baseB + boff[n]);
#pragma unroll
    for (int m = 0; m < 4; ++m) af[m] = *(const f16x8*)(baseA + aoff[m]);
    if (stg) STG_A(t+1, 0, b2);
    __builtin_amdgcn_s_setprio(1);
#pragma unroll
    for (int m = 0; m < 4; ++m)
#pragma unroll
      for (int n = 0; n < 4; ++n) acc[m][n] = MFMA16(af[m], bf[n], acc[m][n]);
    __builtin_amdgcn_s_setprio(0);
#pragma unroll
    for (int m = 0; m < 4; ++m) af[m] = *(const f16x8*)(baseA + aoff[m+4]);
    if (stg) STG_B(t+1, 0, b2);
    __builtin_amdgcn_s_setprio(1);
#pragma unroll
    for (int m = 0; m < 4; ++m)
#pragma unroll
      for (int n = 0; n < 4; ++n) acc[m+4][n] = MFMA16(af[m], bf[n], acc[m+4][n]);
    __builtin_amdgcn_s_setprio(0);
    if (stg) { asm volatile("s_waitcnt vmcnt(4)" ::: "memory"); }
    else     { asm volatile("s_waitcnt vmcnt(0)" ::: "memory"); }
    __builtin_amdgcn_s_barrier();
    asm volatile("" ::: "memory");
#pragma unroll
    for (int n = 0; n < 4; ++n) bf[n] = *(const f16x8*)(baseB + 16384 + boff[n]);
#pragma unroll
    for (int m = 0; m < 4; ++m) af[m] = *(const f16x8*)(baseA + 16384 + aoff[m]);
    if (stg) STG_A(t+1, 1, b2);
    __builtin_amdgcn_s_setprio(1);
#pragma unroll
    for (int m = 0; m < 4; ++m)
#pragma unroll
      for (int n = 0; n < 4; ++n) acc[m][n] = MFMA16(af[m], bf[n], acc[m][n]);
    __builtin_amdgcn_s_setprio(0);
#pragma unroll
    for (int m = 0; m < 4; ++m) af[m] = *(const f16x8*)(baseA + 16384 + aoff[m+4]);
    if (stg) STG_B(t+1, 1, b2);
    __builtin_amdgcn_s_setprio(1);
#pragma unroll
    for (int m = 0; m < 4; ++m)
#pragma unroll
      for (int n = 0; n < 4; ++n) acc[m+4][n] = MFMA16(af[m], bf[n], acc[m+4][n]);
    __builtin_amdgcn_s_setprio(0);
  }

#pragma unroll
  for (int m = 0; m < 8; ++m){
#pragma unroll
    for (int j = 0; j < 4; ++j){
      int li = mt*BM + wm*128 + m*16 + hi*4 + j;
      if (li < cnt){
        int tk = ids[e*STRIDE + li];
        float wv = wts[e*STRIDE + li];
        float* orow = out + (size_t)tk * DMODEL + n0 + wn*64;
#pragma unroll
        for (int n = 0; n < 4; ++n)
          atomicAdd(&orow[n*16 + l15], wv * acc[m][n][j]);
      }
    }
  }
#undef STG_A
#undef STG_B
}

// ---------------- host launch ----------------
extern "C" void kernel_launch(void* const* d_in, const int* in_sizes, int n_in,
                              void* d_out, int out_size, void* d_ws, size_t ws_size,
                              hipStream_t stream)
{
  const float* x  = (const float*)d_in[0];
  const float* wr = (const float*)d_in[1];
  const float* wg = (const float*)d_in[2];
  const float* wu = (const float*)d_in[3];
  const float* wd = (const float*)d_in[4];
  float* out = (float*)d_out;
  char* ws = (char*)d_ws;

  const size_t OFF_IDS = 256;
  const size_t OFF_WTS = OFF_IDS + (size_t)NEXP*STRIDE*4;
  const size_t OFF_XH  = OFF_WTS + (size_t)NEXP*STRIDE*4;
  const size_t OFF_WT  = OFF_XH  + (size_t)NTOK*DMODEL*2;
  const size_t OFF_H   = OFF_WT  + 2*(size_t)NEXP*DMODEL*FFN*2;
  const size_t HROWS   = (size_t)MAXT * BM;               // 36864
  const size_t NEED    = OFF_H + HROWS*FFN*2;
  if (ws_size < NEED){ k_sentinel<<<1,1,0,stream>>>(out); return; }

  int*      counts = (int*)ws;
  int*      ids    = (int*)(ws + OFF_IDS);
  float*    wts    = (float*)(ws + OFF_WTS);
  _Float16* xh     = (_Float16*)(ws + OFF_XH);
  _Float16* wgT    = (_Float16*)(ws + OFF_WT);
  _Float16* wuT    = wgT + (size_t)NEXP*DMODEL*FFN;
  _Float16* wdT    = wgT;                    // alias: written only after k_gateup
  _Float16* H      = (_Float16*)(ws + OFF_H);

  hipMemsetAsync(out, 0, (size_t)out_size * sizeof(float), stream);
  hipMemsetAsync(ws, 0, OFF_XH, stream);     // counts + ids + wts

  dim3 tb(32, 8);
  k_router<<<NTOK, 64, 0, stream>>>(x, wr, counts, ids, wts, xh);
  k_transpose<<<dim3(64,64,16), tb, 0, stream>>>(wg, wgT);
  k_transpose<<<dim3(64,64,16), tb, 0, stream>>>(wu, wuT);
  k_gateup<<<dim3(MAXT, FFN/128), 512, 0, stream>>>(xh, wgT, wuT, counts, ids, H);
  k_transpose<<<dim3(64,64,16), tb, 0, stream>>>(wd, wdT);
  k_down<<<dim3(MAXT, DMODEL/256), 512, 0, stream>>>(H, wdT, counts, ids, wts, out);
}

// Round 3
// 1579.924 us; speedup vs baseline: 1.4650x; 1.1296x over previous
//
#include <hip/hip_runtime.h>
#include <hip/hip_bf16.h>
#include <stdint.h>

// ---------------- problem constants ----------------
#define NTOK   8192
#define DMODEL 2048
#define FFN    2048
#define NEXP   16
#define TOPK   4
#define STRIDE (NTOK + 256)                 // per-expert ids/wts stride

#define BM 256
#define BK 64
#define NKT (DMODEL/BK)                     // 32 K-tiles
#define MAXT ((NTOK*TOPK)/BM + NEXP)        // 144 worst-case M-tiles

typedef __attribute__((ext_vector_type(4))) float    f32x4;
typedef __attribute__((ext_vector_type(4))) _Float16 f16x4;
typedef __attribute__((ext_vector_type(8))) _Float16 f16x8;

typedef __attribute__((address_space(1))) void gvoid;
typedef __attribute__((address_space(3))) void lvoid;
#define GLDS16(gp, lp) __builtin_amdgcn_global_load_lds((gvoid*)(gp), (lvoid*)(lp), 16, 0, 0)

#define MFMA16(a,b,c) __builtin_amdgcn_mfma_f32_16x16x32_f16((a),(b),(c),0,0,0)

// ---------------- prep kernels ----------------

__global__ void k_sentinel(float* o){ o[0] = 3.0e7f; }

// transpose one 2048x2048 fp32 per blockIdx.z into fp16 (dst[c][r] = src[r][c]), vectorized
__global__ __launch_bounds__(256) void k_transpose(const float* __restrict__ src,
                                                   _Float16* __restrict__ dst){
  __shared__ float t[32][33];
  const size_t mo = (size_t)blockIdx.z * DMODEL * FFN;
  const float* S = src + mo;
  _Float16*    D = dst + mo;
  const int tid = threadIdx.x;
  const int x0 = blockIdx.x * 32, y0 = blockIdx.y * 32;
  {
    int row = tid >> 3, c4 = tid & 7;
    float4 v = *(const float4*)(S + (size_t)(y0 + row) * 2048 + x0 + c4*4);
    t[row][c4*4+0] = v.x; t[row][c4*4+1] = v.y; t[row][c4*4+2] = v.z; t[row][c4*4+3] = v.w;
  }
  __syncthreads();
  {
    int oc = tid >> 3, ch = tid & 7;
    f16x4 h;
    h[0] = (_Float16)t[ch*4+0][oc]; h[1] = (_Float16)t[ch*4+1][oc];
    h[2] = (_Float16)t[ch*4+2][oc]; h[3] = (_Float16)t[ch*4+3][oc];
    *(f16x4*)(D + (size_t)(x0 + oc) * 2048 + y0 + ch*4) = h;
  }
}

// ---------------- router (fused with x -> fp16 convert) ----------------
__global__ __launch_bounds__(64) void k_router(const float* __restrict__ x,
                                               const float* __restrict__ wr,
                                               int*   __restrict__ counts,
                                               int*   __restrict__ ids,
                                               float* __restrict__ wts,
                                               int*   __restrict__ slotmap,
                                               float* __restrict__ wk,
                                               _Float16* __restrict__ xh){
  const int t = blockIdx.x, lane = threadIdx.x;
  const float4* x4 = (const float4*)(x + (size_t)t * DMODEL);
  const float4* w4 = (const float4*)wr;
  float acc[NEXP];
#pragma unroll
  for (int e = 0; e < NEXP; ++e) acc[e] = 0.f;
#pragma unroll
  for (int i = 0; i < 8; ++i){
    int d4 = lane + i*64;
    float4 xv = x4[d4];
    f16x4 h; h[0]=(_Float16)xv.x; h[1]=(_Float16)xv.y; h[2]=(_Float16)xv.z; h[3]=(_Float16)xv.w;
    *(f16x4*)(xh + (size_t)t*DMODEL + d4*4) = h;
#pragma unroll
    for (int e = 0; e < NEXP; ++e){
      float4 wv = w4[e*512 + d4];
      acc[e] += xv.x*wv.x + xv.y*wv.y + xv.z*wv.z + xv.w*wv.w;
    }
  }
#pragma unroll
  for (int e = 0; e < NEXP; ++e){
    float v = acc[e];
#pragma unroll
    for (int s = 32; s > 0; s >>= 1) v += __shfl_xor(v, s);
    acc[e] = v;
  }
  if (lane == 0){
    int mask = 0; float tv[TOPK]; int te[TOPK];
    for (int k = 0; k < TOPK; ++k){      // strict '>' keeps lowest index on ties
      float best = -3.0e38f; int bi = 0;
      for (int e = 0; e < NEXP; ++e)
        if (!((mask >> e) & 1) && acc[e] > best){ best = acc[e]; bi = e; }
      mask |= 1 << bi; tv[k] = best; te[k] = bi;
    }
    float m = tv[0], s = 0.f, w[TOPK];
    for (int k = 0; k < TOPK; ++k){ w[k] = __expf(tv[k] - m); s += w[k]; }
    float inv = 1.f / s;
    for (int k = 0; k < TOPK; ++k){
      int slot = atomicAdd(&counts[te[k]], 1);
      ids[te[k]*STRIDE + slot] = t;
      wts[te[k]*STRIDE + slot] = w[k] * inv;
      slotmap[t*TOPK + k] = (te[k] << 16) | slot;
      wk[t*TOPK + k] = w[k] * inv;
    }
  }
}

// ================= grouped GEMM 1: H = silu(X@Wg)*(X@Wu) =================
// 256x256 tile, BK=64, 8 waves (2Mx4N), dbuf LDS 128KB, counted-vmcnt pipeline,
// 2-way-free XOR swizzle, swapped-operand MFMA for vectorized H stores.
__global__ __launch_bounds__(512, 2) void k_gateup(
    const _Float16* __restrict__ xh,
    const _Float16* __restrict__ wgT,   // [E][F][D]
    const _Float16* __restrict__ wuT,
    const int* __restrict__ counts,
    const int* __restrict__ ids,
    _Float16* __restrict__ H)
{
  __shared__ __align__(128) char smem[131072];
  char* ldsA = smem;            // [2 buf][2 half][256 rows][64 B]
  char* ldsB = smem + 65536;

  // XCD-bijective swizzle + 4-N-column grouping (nblk = MAXT*16, %8==0)
  const int bid = blockIdx.x;
  const int vid = (bid & 7) * (MAXT*16/8) + (bid >> 3);
  const int g = vid / (4*MAXT), rem = vid % (4*MAXT);
  const int mt_lin = rem >> 2;
  const int n0 = (g*4 + (rem & 3)) * 128;

  int e = -1, mt = 0, rowbase = 0;
  { int at = 0, rb = 0;
    for (int i = 0; i < NEXP; ++i){
      int c = counts[i]; int nt = (c + 255) >> 8;
      if (e < 0 && mt_lin < at + nt){ e = i; mt = mt_lin - at; rowbase = rb; }
      at += nt; rb += nt * BM;
    } }
  if (e < 0) return;

  const int tid = threadIdx.x, lane = tid & 63, w = tid >> 6;
  const int wm = w >> 2, wn = w & 3, hi = lane >> 4, l15 = lane & 15;
  const int wdst = w * 1024;

  // staging: thread stages rows r=(tid>>2)+128j, LDS chunk position s4=tid&3;
  // source chunk = s4 ^ ((r>>1)&3) so linear-dest LDS == swizzled layout.
  const int jr = tid >> 2, s4 = tid & 3;
  const char* srcA[2]; const char* srcB[2];
#pragma unroll
  for (int j = 0; j < 2; ++j){
    int r = jr + 128*j;
    int sc = (s4 ^ ((r >> 1) & 3)) << 4;
    int tok = ids[e*STRIDE + mt*BM + r];
    srcA[j] = (const char*)(xh + (size_t)tok * DMODEL) + sc;
    int which = (r >> 5) & 1, col = n0 + ((r >> 6) << 5) + (r & 31);
    const _Float16* Wm = which ? wuT : wgT;
    srcB[j] = (const char*)(Wm + ((size_t)e * FFN + col) * (size_t)DMODEL) + sc;
  }

  // frag read offsets: r*64 + ((hi ^ ((r>>1)&3))<<4)  -> 2-way (free) on ds_read_b128
  int aoff[8], boff[4];
#pragma unroll
  for (int m = 0; m < 8; ++m){ int r = wm*128 + m*16 + l15; aoff[m] = r*64 + ((hi ^ ((r>>1)&3)) << 4); }
#pragma unroll
  for (int n = 0; n < 4; ++n){ int r = wn*64  + n*16 + l15; boff[n] = r*64 + ((hi ^ ((r>>1)&3)) << 4); }

  f32x4 acc[8][4];
#pragma unroll
  for (int m = 0; m < 8; ++m)
#pragma unroll
    for (int n = 0; n < 4; ++n) acc[m][n] = (f32x4)(0.0f);

#define STG_A(t,h,b) { _Pragma("unroll") for (int j = 0; j < 2; ++j) \
    GLDS16(srcA[j] + (t)*128 + (h)*64, ldsA + (b)*32768 + (h)*16384 + j*8192 + wdst); }
#define STG_B(t,h,b) { _Pragma("unroll") for (int j = 0; j < 2; ++j) \
    GLDS16(srcB[j] + (t)*128 + (h)*64, ldsB + (b)*32768 + (h)*16384 + j*8192 + wdst); }

  STG_A(0,0,0); STG_B(0,0,0); STG_A(0,1,0); STG_B(0,1,0);

  f16x8 af[4], bf[4];
  for (int t = 0; t < NKT; ++t){
    const int p = t & 1, b2 = p ^ 1;
    const bool stg = (t + 1 < NKT);
    const char* baseA = ldsA + p*32768;
    const char* baseB = ldsB + p*32768;
    asm volatile("s_waitcnt vmcnt(4)" ::: "memory");
    __builtin_amdgcn_s_barrier();
    asm volatile("" ::: "memory");
#pragma unroll
    for (int n = 0; n < 4; ++n) bf[n] = *(const f16x8*)(baseB + boff[n]);
#pragma unroll
    for (int m = 0; m < 4; ++m) af[m] = *(const f16x8*)(baseA + aoff[m]);
    if (stg) STG_A(t+1, 0, b2);
    __builtin_amdgcn_s_setprio(1);
#pragma unroll
    for (int m = 0; m < 4; ++m)
#pragma unroll
      for (int n = 0; n < 4; ++n) acc[m][n] = MFMA16(bf[n], af[m], acc[m][n]);
    __builtin_amdgcn_s_setprio(0);
#pragma unroll
    for (int m = 0; m < 4; ++m) af[m] = *(const f16x8*)(baseA + aoff[m+4]);
    if (stg) STG_B(t+1, 0, b2);
    __builtin_amdgcn_s_setprio(1);
#pragma unroll
    for (int m = 0; m < 4; ++m)
#pragma unroll
      for (int n = 0; n < 4; ++n) acc[m+4][n] = MFMA16(bf[n], af[m], acc[m+4][n]);
    __builtin_amdgcn_s_setprio(0);
    if (stg) { asm volatile("s_waitcnt vmcnt(4)" ::: "memory"); }
    else     { asm volatile("s_waitcnt vmcnt(0)" ::: "memory"); }
    __builtin_amdgcn_s_barrier();
    asm volatile("" ::: "memory");
#pragma unroll
    for (int n = 0; n < 4; ++n) bf[n] = *(const f16x8*)(baseB + 16384 + boff[n]);
#pragma unroll
    for (int m = 0; m < 4; ++m) af[m] = *(const f16x8*)(baseA + 16384 + aoff[m]);
    if (stg) STG_A(t+1, 1, b2);
    __builtin_amdgcn_s_setprio(1);
#pragma unroll
    for (int m = 0; m < 4; ++m)
#pragma unroll
      for (int n = 0; n < 4; ++n) acc[m][n] = MFMA16(bf[n], af[m], acc[m][n]);
    __builtin_amdgcn_s_setprio(0);
#pragma unroll
    for (int m = 0; m < 4; ++m) af[m] = *(const f16x8*)(baseA + 16384 + aoff[m+4]);
    if (stg) STG_B(t+1, 1, b2);
    __builtin_amdgcn_s_setprio(1);
#pragma unroll
    for (int m = 0; m < 4; ++m)
#pragma unroll
      for (int n = 0; n < 4; ++n) acc[m+4][n] = MFMA16(bf[n], af[m], acc[m+4][n]);
    __builtin_amdgcn_s_setprio(0);
  }

  // swapped layout: lane holds token = base+l15, F-cols = n0+wn*32+nf*16+hi*4+j (j=0..3)
  const int hrow0 = rowbase + mt*BM + wm*128;
#pragma unroll
  for (int m = 0; m < 8; ++m){
    int row = hrow0 + m*16 + l15;
#pragma unroll
    for (int nf = 0; nf < 2; ++nf){
      f16x4 hv;
#pragma unroll
      for (int j = 0; j < 4; ++j){
        float g = acc[m][nf][j], u = acc[m][nf+2][j];
        hv[j] = (_Float16)(g / (1.f + __expf(-g)) * u);
      }
      *(f16x4*)(H + (size_t)row * FFN + n0 + wn*32 + nf*16 + hi*4) = hv;
    }
  }
#undef STG_A
#undef STG_B
}

// ================= grouped GEMM 2: Ydown (or atomic out) = H @ Wd =================
__global__ __launch_bounds__(512, 2) void k_down(
    const _Float16* __restrict__ H,
    const _Float16* __restrict__ wdT,   // [E][D][F]
    const int* __restrict__ counts,
    const int* __restrict__ ids,
    const float* __restrict__ wts,
    _Float16* __restrict__ Y,
    float* __restrict__ out,
    int useY)
{
  __shared__ __align__(128) char smem[131072];
  char* ldsA = smem;
  char* ldsB = smem + 65536;

  const int bid = blockIdx.x;
  const int vid = (bid & 7) * (MAXT*8/8) + (bid >> 3);
  const int g = vid / (4*MAXT), rem = vid % (4*MAXT);
  const int mt_lin = rem >> 2;
  const int n0 = (g*4 + (rem & 3)) * 256;

  int e = -1, mt = 0, rowbase = 0, cnt = 0;
  { int at = 0, rb = 0;
    for (int i = 0; i < NEXP; ++i){
      int c = counts[i]; int nt = (c + 255) >> 8;
      if (e < 0 && mt_lin < at + nt){ e = i; mt = mt_lin - at; rowbase = rb; cnt = c; }
      at += nt; rb += nt * BM;
    } }
  if (e < 0) return;

  const int tid = threadIdx.x, lane = tid & 63, w = tid >> 6;
  const int wm = w >> 2, wn = w & 3, hi = lane >> 4, l15 = lane & 15;
  const int wdst = w * 1024;

  const int jr = tid >> 2, s4 = tid & 3;
  const char* srcA[2]; const char* srcB[2];
#pragma unroll
  for (int j = 0; j < 2; ++j){
    int r = jr + 128*j;
    int sc = (s4 ^ ((r >> 1) & 3)) << 4;
    srcA[j] = (const char*)(H   + (size_t)(rowbase + mt*BM + r) * FFN) + sc;
    srcB[j] = (const char*)(wdT + ((size_t)e * DMODEL + n0 + r) * (size_t)FFN) + sc;
  }

  int aoff[8], boff[4];
#pragma unroll
  for (int m = 0; m < 8; ++m){ int r = wm*128 + m*16 + l15; aoff[m] = r*64 + ((hi ^ ((r>>1)&3)) << 4); }
#pragma unroll
  for (int n = 0; n < 4; ++n){ int r = wn*64  + n*16 + l15; boff[n] = r*64 + ((hi ^ ((r>>1)&3)) << 4); }

  f32x4 acc[8][4];
#pragma unroll
  for (int m = 0; m < 8; ++m)
#pragma unroll
    for (int n = 0; n < 4; ++n) acc[m][n] = (f32x4)(0.0f);

#define STG_A(t,h,b) { _Pragma("unroll") for (int j = 0; j < 2; ++j) \
    GLDS16(srcA[j] + (t)*128 + (h)*64, ldsA + (b)*32768 + (h)*16384 + j*8192 + wdst); }
#define STG_B(t,h,b) { _Pragma("unroll") for (int j = 0; j < 2; ++j) \
    GLDS16(srcB[j] + (t)*128 + (h)*64, ldsB + (b)*32768 + (h)*16384 + j*8192 + wdst); }

  STG_A(0,0,0); STG_B(0,0,0); STG_A(0,1,0); STG_B(0,1,0);

  f16x8 af[4], bf[4];
  for (int t = 0; t < NKT; ++t){
    const int p = t & 1, b2 = p ^ 1;
    const bool stg = (t + 1 < NKT);
    const char* baseA = ldsA + p*32768;
    const char* baseB = ldsB + p*32768;
    asm volatile("s_waitcnt vmcnt(4)" ::: "memory");
    __builtin_amdgcn_s_barrier();
    asm volatile("" ::: "memory");
#pragma unroll
    for (int n = 0; n < 4; ++n) bf[n] = *(const f16x8*)(baseB + boff[n]);
#pragma unroll
    for (int m = 0; m < 4; ++m) af[m] = *(const f16x8*)(baseA + aoff[m]);
    if (stg) STG_A(t+1, 0, b2);
    __builtin_amdgcn_s_setprio(1);
#pragma unroll
    for (int m = 0; m < 4; ++m)
#pragma unroll
      for (int n = 0; n < 4; ++n) acc[m][n] = MFMA16(bf[n], af[m], acc[m][n]);
    __builtin_amdgcn_s_setprio(0);
#pragma unroll
    for (int m = 0; m < 4; ++m) af[m] = *(const f16x8*)(baseA + aoff[m+4]);
    if (stg) STG_B(t+1, 0, b2);
    __builtin_amdgcn_s_setprio(1);
#pragma unroll
    for (int m = 0; m < 4; ++m)
#pragma unroll
      for (int n = 0; n < 4; ++n) acc[m+4][n] = MFMA16(bf[n], af[m], acc[m+4][n]);
    __builtin_amdgcn_s_setprio(0);
    if (stg) { asm volatile("s_waitcnt vmcnt(4)" ::: "memory"); }
    else     { asm volatile("s_waitcnt vmcnt(0)" ::: "memory"); }
    __builtin_amdgcn_s_barrier();
    asm volatile("" ::: "memory");
#pragma unroll
    for (int n = 0; n < 4; ++n) bf[n] = *(const f16x8*)(baseB + 16384 + boff[n]);
#pragma unroll
    for (int m = 0; m < 4; ++m) af[m] = *(const f16x8*)(baseA + 16384 + aoff[m]);
    if (stg) STG_A(t+1, 1, b2);
    __builtin_amdgcn_s_setprio(1);
#pragma unroll
    for (int m = 0; m < 4; ++m)
#pragma unroll
      for (int n = 0; n < 4; ++n) acc[m][n] = MFMA16(bf[n], af[m], acc[m][n]);
    __builtin_amdgcn_s_setprio(0);
#pragma unroll
    for (int m = 0; m < 4; ++m) af[m] = *(const f16x8*)(baseA + 16384 + aoff[m+4]);
    if (stg) STG_B(t+1, 1, b2);
    __builtin_amdgcn_s_setprio(1);
#pragma unroll
    for (int m = 0; m < 4; ++m)
#pragma unroll
      for (int n = 0; n < 4; ++n) acc[m+4][n] = MFMA16(bf[n], af[m], acc[m+4][n]);
    __builtin_amdgcn_s_setprio(0);
  }

  // swapped layout: lane holds row = base+l15, D-cols = n0+wn*64+n*16+hi*4+j
  if (useY){
#pragma unroll
    for (int m = 0; m < 8; ++m){
      size_t yrow = (size_t)(rowbase + mt*BM + wm*128 + m*16 + l15) * DMODEL;
#pragma unroll
      for (int n = 0; n < 4; ++n){
        f16x4 yv;
#pragma unroll
        for (int j = 0; j < 4; ++j) yv[j] = (_Float16)acc[m][n][j];
        *(f16x4*)(Y + yrow + n0 + wn*64 + n*16 + hi*4) = yv;
      }
    }
  } else {
#pragma unroll
    for (int m = 0; m < 8; ++m){
      int li = mt*BM + wm*128 + m*16 + l15;
      if (li < cnt){
        int tk = ids[e*STRIDE + li];
        float wv = wts[e*STRIDE + li];
        float* orow = out + (size_t)tk * DMODEL + n0 + wn*64;
#pragma unroll
        for (int n = 0; n < 4; ++n)
#pragma unroll
          for (int j = 0; j < 4; ++j)
            atomicAdd(&orow[n*16 + hi*4 + j], wv * acc[m][n][j]);
      }
    }
  }
#undef STG_A
#undef STG_B
}

// ---------------- combine: out[t] = sum_k wk * Y[slot_k] ----------------
__global__ __launch_bounds__(256) void k_combine(const _Float16* __restrict__ Y,
                                                 const int* __restrict__ counts,
                                                 const int* __restrict__ slotmap,
                                                 const float* __restrict__ wk,
                                                 float* __restrict__ out){
  __shared__ int pre[NEXP];
  const int t = blockIdx.x, c = threadIdx.x;
  if (c == 0){
    int a = 0;
    for (int i = 0; i < NEXP; ++i){ pre[i] = a; a += ((counts[i] + 255) >> 8) << 8; }
  }
  __syncthreads();
  float o[8];
#pragma unroll
  for (int i = 0; i < 8; ++i) o[i] = 0.f;
#pragma unroll
  for (int k = 0; k < TOPK; ++k){
    int sm = slotmap[t*TOPK + k];
    int row = pre[sm >> 16] + (sm & 0xffff);
    float wv = wk[t*TOPK + k];
    f16x8 y = *(const f16x8*)(Y + (size_t)row * DMODEL + c*8);
#pragma unroll
    for (int i = 0; i < 8; ++i) o[i] += wv * (float)y[i];
  }
  float4 lo = {o[0], o[1], o[2], o[3]}, hu = {o[4], o[5], o[6], o[7]};
  float* op = out + (size_t)t * DMODEL + c*8;
  *(float4*)op = lo;
  *(float4*)(op + 4) = hu;
}

// ---------------- host launch ----------------
extern "C" void kernel_launch(void* const* d_in, const int* in_sizes, int n_in,
                              void* d_out, int out_size, void* d_ws, size_t ws_size,
                              hipStream_t stream)
{
  const float* x  = (const float*)d_in[0];
  const float* wr = (const float*)d_in[1];
  const float* wg = (const float*)d_in[2];
  const float* wu = (const float*)d_in[3];
  const float* wd = (const float*)d_in[4];
  float* out = (float*)d_out;
  char* ws = (char*)d_ws;

  const size_t OFF_IDS  = 256;
  const size_t OFF_WTS  = OFF_IDS + (size_t)NEXP*STRIDE*4;
  const size_t OFF_SLOT = OFF_WTS + (size_t)NEXP*STRIDE*4;
  const size_t OFF_WK   = OFF_SLOT + (size_t)NTOK*TOPK*4;
  const size_t OFF_XH   = OFF_WK  + (size_t)NTOK*TOPK*4;
  const size_t OFF_WT   = OFF_XH  + (size_t)NTOK*DMODEL*2;
  const size_t OFF_H    = OFF_WT  + 2*(size_t)NEXP*DMODEL*FFN*2;
  const size_t HROWS    = (size_t)MAXT * BM;               // 36864
  const size_t HBYTES   = HROWS * FFN * 2;
  const size_t NEED     = OFF_H + HBYTES;
  const size_t OFF_Y    = NEED;
  const size_t NEED_Y   = OFF_Y + HROWS * DMODEL * 2;
  if (ws_size < NEED){ k_sentinel<<<1,1,0,stream>>>(out); return; }
  const int useY = (ws_size >= NEED_Y) ? 1 : 0;

  int*      counts = (int*)ws;
  int*      ids    = (int*)(ws + OFF_IDS);
  float*    wts    = (float*)(ws + OFF_WTS);
  int*      slotmap= (int*)(ws + OFF_SLOT);
  float*    wk     = (float*)(ws + OFF_WK);
  _Float16* xh     = (_Float16*)(ws + OFF_XH);
  _Float16* wgT    = (_Float16*)(ws + OFF_WT);
  _Float16* wuT    = wgT + (size_t)NEXP*DMODEL*FFN;
  _Float16* wdT    = wgT;                    // alias: written only after k_gateup
  _Float16* H      = (_Float16*)(ws + OFF_H);
  _Float16* Y      = (_Float16*)(ws + OFF_Y);

  hipMemsetAsync(ws, 0, OFF_SLOT, stream);   // counts + ids + wts
  if (!useY) hipMemsetAsync(out, 0, (size_t)out_size * sizeof(float), stream);

  k_router<<<NTOK, 64, 0, stream>>>(x, wr, counts, ids, wts, slotmap, wk, xh);
  k_transpose<<<dim3(64,64,16), 256, 0, stream>>>(wg, wgT);
  k_transpose<<<dim3(64,64,16), 256, 0, stream>>>(wu, wuT);
  k_gateup<<<MAXT*16, 512, 0, stream>>>(xh, wgT, wuT, counts, ids, H);
  k_transpose<<<dim3(64,64,16), 256, 0, stream>>>(wd, wdT);
  k_down<<<MAXT*8, 512, 0, stream>>>(H, wdT, counts, ids, wts, Y, out, useY);
  if (useY) k_combine<<<NTOK, 256, 0, stream>>>(Y, counts, slotmap, wk, out);
}

// Round 4
// 1576.317 us; speedup vs baseline: 1.4683x; 1.0023x over previous
//
#include <hip/hip_runtime.h>
#include <hip/hip_bf16.h>
#include <stdint.h>

// ---------------- problem constants ----------------
#define NTOK   8192
#define DMODEL 2048
#define FFN    2048
#define NEXP   16
#define TOPK   4
#define STRIDE (NTOK + 256)                 // per-expert ids stride

#define BM 256
#define BK 64
#define NKT (DMODEL/BK)                     // 32 K-tiles
#define MAXT ((NTOK*TOPK)/BM + NEXP)        // 144 worst-case M-tiles

typedef __attribute__((ext_vector_type(4))) float    f32x4;
typedef __attribute__((ext_vector_type(4))) _Float16 f16x4;
typedef __attribute__((ext_vector_type(8))) _Float16 f16x8;

typedef __attribute__((address_space(1))) void gvoid;
typedef __attribute__((address_space(3))) void lvoid;
#define GLDS16(gp, lp) __builtin_amdgcn_global_load_lds((gvoid*)(gp), (lvoid*)(lp), 16, 0, 0)

#define MFMA16(a,b,c) __builtin_amdgcn_mfma_f32_16x16x32_f16((a),(b),(c),0,0,0)

// ---------------- prep kernels ----------------

__global__ void k_sentinel(float* o){ o[0] = 3.0e7f; }   // ws too small marker

// transpose one 2048x2048 fp32 per blockIdx.z into fp16 (dst[c][r] = src[r][c])
__global__ __launch_bounds__(256) void k_transpose(const float* __restrict__ src,
                                                   _Float16* __restrict__ dst){
  __shared__ float t[32][33];
  const size_t mo = (size_t)blockIdx.z * DMODEL * FFN;
  const float* S = src + mo;
  _Float16*    D = dst + mo;
  const int tid = threadIdx.x;
  const int x0 = blockIdx.x * 32, y0 = blockIdx.y * 32;
  {
    int row = tid >> 3, c4 = tid & 7;
    float4 v = *(const float4*)(S + (size_t)(y0 + row) * 2048 + x0 + c4*4);
    t[row][c4*4+0] = v.x; t[row][c4*4+1] = v.y; t[row][c4*4+2] = v.z; t[row][c4*4+3] = v.w;
  }
  __syncthreads();
  {
    int oc = tid >> 3, ch = tid & 7;
    f16x4 h;
    h[0] = (_Float16)t[ch*4+0][oc]; h[1] = (_Float16)t[ch*4+1][oc];
    h[2] = (_Float16)t[ch*4+2][oc]; h[3] = (_Float16)t[ch*4+3][oc];
    *(f16x4*)(D + (size_t)(x0 + oc) * 2048 + y0 + ch*4) = h;
  }
}

// ---------------- router (fused with x -> fp16 convert) ----------------
__global__ __launch_bounds__(64) void k_router(const float* __restrict__ x,
                                               const float* __restrict__ wr,
                                               int*   __restrict__ counts,
                                               int*   __restrict__ ids,
                                               int*   __restrict__ slotmap,
                                               float* __restrict__ wk,
                                               _Float16* __restrict__ xh){
  const int t = blockIdx.x, lane = threadIdx.x;
  const float4* x4 = (const float4*)(x + (size_t)t * DMODEL);
  const float4* w4 = (const float4*)wr;
  float acc[NEXP];
#pragma unroll
  for (int e = 0; e < NEXP; ++e) acc[e] = 0.f;
#pragma unroll
  for (int i = 0; i < 8; ++i){
    int d4 = lane + i*64;
    float4 xv = x4[d4];
    f16x4 h; h[0]=(_Float16)xv.x; h[1]=(_Float16)xv.y; h[2]=(_Float16)xv.z; h[3]=(_Float16)xv.w;
    *(f16x4*)(xh + (size_t)t*DMODEL + d4*4) = h;
#pragma unroll
    for (int e = 0; e < NEXP; ++e){
      float4 wv = w4[e*512 + d4];
      acc[e] += xv.x*wv.x + xv.y*wv.y + xv.z*wv.z + xv.w*wv.w;
    }
  }
#pragma unroll
  for (int e = 0; e < NEXP; ++e){
    float v = acc[e];
#pragma unroll
    for (int s = 32; s > 0; s >>= 1) v += __shfl_xor(v, s);
    acc[e] = v;
  }
  if (lane == 0){
    int mask = 0; float tv[TOPK]; int te[TOPK];
    for (int k = 0; k < TOPK; ++k){      // strict '>' keeps lowest index on ties
      float best = -3.0e38f; int bi = 0;
      for (int e = 0; e < NEXP; ++e)
        if (!((mask >> e) & 1) && acc[e] > best){ best = acc[e]; bi = e; }
      mask |= 1 << bi; tv[k] = best; te[k] = bi;
    }
    float m = tv[0], s = 0.f, w[TOPK];
    for (int k = 0; k < TOPK; ++k){ w[k] = __expf(tv[k] - m); s += w[k]; }
    float inv = 1.f / s;
    for (int k = 0; k < TOPK; ++k){
      int slot = atomicAdd(&counts[te[k]], 1);
      ids[te[k]*STRIDE + slot] = t;
      slotmap[t*TOPK + k] = (te[k] << 16) | slot;
      wk[t*TOPK + k] = w[k] * inv;
    }
  }
}

// ================= grouped GEMM 1: H = silu(X@Wg)*(X@Wu) =================
// 256x256 tile, BK=64, 8 waves (2Mx4N), dbuf LDS 128KB, counted-vmcnt pipeline,
// 2-way-free XOR swizzle, swapped-operand MFMA for vectorized H stores.
__global__ __launch_bounds__(512, 2) void k_gateup(
    const _Float16* __restrict__ xh,
    const _Float16* __restrict__ wgT,   // [E][F][D]
    const _Float16* __restrict__ wuT,
    const int* __restrict__ counts,
    const int* __restrict__ ids,
    _Float16* __restrict__ H)
{
  __shared__ __align__(128) char smem[131072];
  char* ldsA = smem;            // [2 buf][2 half][256 rows][64 B]
  char* ldsB = smem + 65536;

  // XCD-bijective swizzle + 4-N-column grouping (grid = MAXT*16, %8==0)
  const int bid = blockIdx.x;
  const int vid = (bid & 7) * (MAXT*16/8) + (bid >> 3);
  const int g = vid / (4*MAXT), rem = vid % (4*MAXT);
  const int mt_lin = rem >> 2;
  const int n0 = (g*4 + (rem & 3)) * 128;

  int e = -1, mt = 0, rowbase = 0;
  { int at = 0, rb = 0;
    for (int i = 0; i < NEXP; ++i){
      int c = counts[i]; int nt = (c + 255) >> 8;
      if (e < 0 && mt_lin < at + nt){ e = i; mt = mt_lin - at; rowbase = rb; }
      at += nt; rb += nt * BM;
    } }
  if (e < 0) return;

  const int tid = threadIdx.x, lane = tid & 63, w = tid >> 6;
  const int wm = w >> 2, wn = w & 3, hi = lane >> 4, l15 = lane & 15;
  const int wdst = w * 1024;

  // staging: thread stages rows r=(tid>>2)+128j, LDS chunk position s4=tid&3;
  // source chunk = s4 ^ ((r>>1)&3) so linear-dest LDS == swizzled layout.
  const int jr = tid >> 2, s4 = tid & 3;
  const char* srcA[2]; const char* srcB[2];
#pragma unroll
  for (int j = 0; j < 2; ++j){
    int r = jr + 128*j;
    int sc = (s4 ^ ((r >> 1) & 3)) << 4;
    int tok = ids[e*STRIDE + mt*BM + r];
    srcA[j] = (const char*)(xh + (size_t)tok * DMODEL) + sc;
    int which = (r >> 5) & 1, col = n0 + ((r >> 6) << 5) + (r & 31);
    const _Float16* Wm = which ? wuT : wgT;
    srcB[j] = (const char*)(Wm + ((size_t)e * FFN + col) * (size_t)DMODEL) + sc;
  }

  // frag read offsets: r*64 + ((hi ^ ((r>>1)&3))<<4)  -> 2-way (free) on ds_read_b128
  int aoff[8], boff[4];
#pragma unroll
  for (int m = 0; m < 8; ++m){ int r = wm*128 + m*16 + l15; aoff[m] = r*64 + ((hi ^ ((r>>1)&3)) << 4); }
#pragma unroll
  for (int n = 0; n < 4; ++n){ int r = wn*64  + n*16 + l15; boff[n] = r*64 + ((hi ^ ((r>>1)&3)) << 4); }

  f32x4 acc[8][4];
#pragma unroll
  for (int m = 0; m < 8; ++m)
#pragma unroll
    for (int n = 0; n < 4; ++n) acc[m][n] = (f32x4)(0.0f);

#define STG_A(t,h,b) { _Pragma("unroll") for (int j = 0; j < 2; ++j) \
    GLDS16(srcA[j] + (t)*128 + (h)*64, ldsA + (b)*32768 + (h)*16384 + j*8192 + wdst); }
#define STG_B(t,h,b) { _Pragma("unroll") for (int j = 0; j < 2; ++j) \
    GLDS16(srcB[j] + (t)*128 + (h)*64, ldsB + (b)*32768 + (h)*16384 + j*8192 + wdst); }

  STG_A(0,0,0); STG_B(0,0,0); STG_A(0,1,0); STG_B(0,1,0);

  f16x8 af[4], bf[4];
  for (int t = 0; t < NKT; ++t){
    const int p = t & 1, b2 = p ^ 1;
    const bool stg = (t + 1 < NKT);
    const char* baseA = ldsA + p*32768;
    const char* baseB = ldsB + p*32768;
    asm volatile("s_waitcnt vmcnt(4)" ::: "memory");
    __builtin_amdgcn_s_barrier();
    asm volatile("" ::: "memory");
#pragma unroll
    for (int n = 0; n < 4; ++n) bf[n] = *(const f16x8*)(baseB + boff[n]);
#pragma unroll
    for (int m = 0; m < 4; ++m) af[m] = *(const f16x8*)(baseA + aoff[m]);
    if (stg) STG_A(t+1, 0, b2);
    __builtin_amdgcn_s_setprio(1);
#pragma unroll
    for (int m = 0; m < 4; ++m)
#pragma unroll
      for (int n = 0; n < 4; ++n) acc[m][n] = MFMA16(bf[n], af[m], acc[m][n]);
    __builtin_amdgcn_s_setprio(0);
#pragma unroll
    for (int m = 0; m < 4; ++m) af[m] = *(const f16x8*)(baseA + aoff[m+4]);
    if (stg) STG_B(t+1, 0, b2);
    __builtin_amdgcn_s_setprio(1);
#pragma unroll
    for (int m = 0; m < 4; ++m)
#pragma unroll
      for (int n = 0; n < 4; ++n) acc[m+4][n] = MFMA16(bf[n], af[m], acc[m+4][n]);
    __builtin_amdgcn_s_setprio(0);
    if (stg) { asm volatile("s_waitcnt vmcnt(4)" ::: "memory"); }
    else     { asm volatile("s_waitcnt vmcnt(0)" ::: "memory"); }
    __builtin_amdgcn_s_barrier();
    asm volatile("" ::: "memory");
#pragma unroll
    for (int n = 0; n < 4; ++n) bf[n] = *(const f16x8*)(baseB + 16384 + boff[n]);
#pragma unroll
    for (int m = 0; m < 4; ++m) af[m] = *(const f16x8*)(baseA + 16384 + aoff[m]);
    if (stg) STG_A(t+1, 1, b2);
    __builtin_amdgcn_s_setprio(1);
#pragma unroll
    for (int m = 0; m < 4; ++m)
#pragma unroll
      for (int n = 0; n < 4; ++n) acc[m][n] = MFMA16(bf[n], af[m], acc[m][n]);
    __builtin_amdgcn_s_setprio(0);
#pragma unroll
    for (int m = 0; m < 4; ++m) af[m] = *(const f16x8*)(baseA + 16384 + aoff[m+4]);
    if (stg) STG_B(t+1, 1, b2);
    __builtin_amdgcn_s_setprio(1);
#pragma unroll
    for (int m = 0; m < 4; ++m)
#pragma unroll
      for (int n = 0; n < 4; ++n) acc[m+4][n] = MFMA16(bf[n], af[m], acc[m+4][n]);
    __builtin_amdgcn_s_setprio(0);
  }

  // swapped layout: lane holds token = base+l15, F-cols = n0+wn*32+nf*16+hi*4+j
  const int hrow0 = rowbase + mt*BM + wm*128;
#pragma unroll
  for (int m = 0; m < 8; ++m){
    int row = hrow0 + m*16 + l15;
#pragma unroll
    for (int nf = 0; nf < 2; ++nf){
      f16x4 hv;
#pragma unroll
      for (int j = 0; j < 4; ++j){
        float g = acc[m][nf][j], u = acc[m][nf+2][j];
        hv[j] = (_Float16)(g / (1.f + __expf(-g)) * u);
      }
      *(f16x4*)(H + (size_t)row * FFN + n0 + wn*32 + nf*16 + hi*4) = hv;
    }
  }
#undef STG_A
#undef STG_B
}

// ================= grouped GEMM 2: Y = H @ Wd (plain stores, split Y buffer) =================
__global__ __launch_bounds__(512, 2) void k_down(
    const _Float16* __restrict__ H,
    const _Float16* __restrict__ wdT,   // [E][D][F]
    const int* __restrict__ counts,
    _Float16* __restrict__ Yw2,         // rows < 32768  (dead wuT region)
    _Float16* __restrict__ Yxh)         // rows >= 32768 (dead xh region)
{
  __shared__ __align__(128) char smem[131072];
  char* ldsA = smem;
  char* ldsB = smem + 65536;

  const int bid = blockIdx.x;
  const int vid = (bid & 7) * MAXT + (bid >> 3);       // grid = MAXT*8
  const int g = vid / (4*MAXT), rem = vid % (4*MAXT);
  const int mt_lin = rem >> 2;
  const int n0 = (g*4 + (rem & 3)) * 256;

  int e = -1, mt = 0, rowbase = 0;
  { int at = 0, rb = 0;
    for (int i = 0; i < NEXP; ++i){
      int c = counts[i]; int nt = (c + 255) >> 8;
      if (e < 0 && mt_lin < at + nt){ e = i; mt = mt_lin - at; rowbase = rb; }
      at += nt; rb += nt * BM;
    } }
  if (e < 0) return;

  const int tid = threadIdx.x, lane = tid & 63, w = tid >> 6;
  const int wm = w >> 2, wn = w & 3, hi = lane >> 4, l15 = lane & 15;
  const int wdst = w * 1024;

  const int jr = tid >> 2, s4 = tid & 3;
  const char* srcA[2]; const char* srcB[2];
#pragma unroll
  for (int j = 0; j < 2; ++j){
    int r = jr + 128*j;
    int sc = (s4 ^ ((r >> 1) & 3)) << 4;
    srcA[j] = (const char*)(H   + (size_t)(rowbase + mt*BM + r) * FFN) + sc;
    srcB[j] = (const char*)(wdT + ((size_t)e * DMODEL + n0 + r) * (size_t)FFN) + sc;
  }

  int aoff[8], boff[4];
#pragma unroll
  for (int m = 0; m < 8; ++m){ int r = wm*128 + m*16 + l15; aoff[m] = r*64 + ((hi ^ ((r>>1)&3)) << 4); }
#pragma unroll
  for (int n = 0; n < 4; ++n){ int r = wn*64  + n*16 + l15; boff[n] = r*64 + ((hi ^ ((r>>1)&3)) << 4); }

  f32x4 acc[8][4];
#pragma unroll
  for (int m = 0; m < 8; ++m)
#pragma unroll
    for (int n = 0; n < 4; ++n) acc[m][n] = (f32x4)(0.0f);

#define STG_A(t,h,b) { _Pragma("unroll") for (int j = 0; j < 2; ++j) \
    GLDS16(srcA[j] + (t)*128 + (h)*64, ldsA + (b)*32768 + (h)*16384 + j*8192 + wdst); }
#define STG_B(t,h,b) { _Pragma("unroll") for (int j = 0; j < 2; ++j) \
    GLDS16(srcB[j] + (t)*128 + (h)*64, ldsB + (b)*32768 + (h)*16384 + j*8192 + wdst); }

  STG_A(0,0,0); STG_B(0,0,0); STG_A(0,1,0); STG_B(0,1,0);

  f16x8 af[4], bf[4];
  for (int t = 0; t < NKT; ++t){
    const int p = t & 1, b2 = p ^ 1;
    const bool stg = (t + 1 < NKT);
    const char* baseA = ldsA + p*32768;
    const char* baseB = ldsB + p*32768;
    asm volatile("s_waitcnt vmcnt(4)" ::: "memory");
    __builtin_amdgcn_s_barrier();
    asm volatile("" ::: "memory");
#pragma unroll
    for (int n = 0; n < 4; ++n) bf[n] = *(const f16x8*)(baseB + boff[n]);
#pragma unroll
    for (int m = 0; m < 4; ++m) af[m] = *(const f16x8*)(baseA + aoff[m]);
    if (stg) STG_A(t+1, 0, b2);
    __builtin_amdgcn_s_setprio(1);
#pragma unroll
    for (int m = 0; m < 4; ++m)
#pragma unroll
      for (int n = 0; n < 4; ++n) acc[m][n] = MFMA16(bf[n], af[m], acc[m][n]);
    __builtin_amdgcn_s_setprio(0);
#pragma unroll
    for (int m = 0; m < 4; ++m) af[m] = *(const f16x8*)(baseA + aoff[m+4]);
    if (stg) STG_B(t+1, 0, b2);
    __builtin_amdgcn_s_setprio(1);
#pragma unroll
    for (int m = 0; m < 4; ++m)
#pragma unroll
      for (int n = 0; n < 4; ++n) acc[m+4][n] = MFMA16(bf[n], af[m], acc[m+4][n]);
    __builtin_amdgcn_s_setprio(0);
    if (stg) { asm volatile("s_waitcnt vmcnt(4)" ::: "memory"); }
    else     { asm volatile("s_waitcnt vmcnt(0)" ::: "memory"); }
    __builtin_amdgcn_s_barrier();
    asm volatile("" ::: "memory");
#pragma unroll
    for (int n = 0; n < 4; ++n) bf[n] = *(const f16x8*)(baseB + 16384 + boff[n]);
#pragma unroll
    for (int m = 0; m < 4; ++m) af[m] = *(const f16x8*)(baseA + 16384 + aoff[m]);
    if (stg) STG_A(t+1, 1, b2);
    __builtin_amdgcn_s_setprio(1);
#pragma unroll
    for (int m = 0; m < 4; ++m)
#pragma unroll
      for (int n = 0; n < 4; ++n) acc[m][n] = MFMA16(bf[n], af[m], acc[m][n]);
    __builtin_amdgcn_s_setprio(0);
#pragma unroll
    for (int m = 0; m < 4; ++m) af[m] = *(const f16x8*)(baseA + 16384 + aoff[m+4]);
    if (stg) STG_B(t+1, 1, b2);
    __builtin_amdgcn_s_setprio(1);
#pragma unroll
    for (int m = 0; m < 4; ++m)
#pragma unroll
      for (int n = 0; n < 4; ++n) acc[m+4][n] = MFMA16(bf[n], af[m], acc[m+4][n]);
    __builtin_amdgcn_s_setprio(0);
  }

  // swapped layout: lane holds row = base+l15, D-cols = n0+wn*64+n*16+hi*4+j
  const int row0 = rowbase + mt*BM + wm*128;
#pragma unroll
  for (int m = 0; m < 8; ++m){
    int row = row0 + m*16 + l15;
    _Float16* yb = (row < 32768) ? (Yw2 + (size_t)row * DMODEL)
                                 : (Yxh + (size_t)(row - 32768) * DMODEL);
#pragma unroll
    for (int n = 0; n < 4; ++n){
      f16x4 yv;
#pragma unroll
      for (int j = 0; j < 4; ++j) yv[j] = (_Float16)acc[m][n][j];
      *(f16x4*)(yb + n0 + wn*64 + n*16 + hi*4) = yv;
    }
  }
#undef STG_A
#undef STG_B
}

// ---------------- combine: out[t] = sum_k wk * Y[slot_k] ----------------
__global__ __launch_bounds__(256) void k_combine(const _Float16* __restrict__ Yw2,
                                                 const _Float16* __restrict__ Yxh,
                                                 const int* __restrict__ counts,
                                                 const int* __restrict__ slotmap,
                                                 const float* __restrict__ wk,
                                                 float* __restrict__ out){
  __shared__ int pre[NEXP];
  const int t = blockIdx.x, c = threadIdx.x;
  if (c == 0){
    int a = 0;
    for (int i = 0; i < NEXP; ++i){ pre[i] = a; a += ((counts[i] + 255) >> 8) << 8; }
  }
  __syncthreads();
  float o[8];
#pragma unroll
  for (int i = 0; i < 8; ++i) o[i] = 0.f;
#pragma unroll
  for (int k = 0; k < TOPK; ++k){
    int sm = slotmap[t*TOPK + k];
    int row = pre[sm >> 16] + (sm & 0xffff);
    float wv = wk[t*TOPK + k];
    const _Float16* yb = (row < 32768) ? (Yw2 + (size_t)row * DMODEL)
                                       : (Yxh + (size_t)(row - 32768) * DMODEL);
    f16x8 y = *(const f16x8*)(yb + c*8);
#pragma unroll
    for (int i = 0; i < 8; ++i) o[i] += wv * (float)y[i];
  }
  float4 lo = {o[0], o[1], o[2], o[3]}, hu = {o[4], o[5], o[6], o[7]};
  float* op = out + (size_t)t * DMODEL + c*8;
  *(float4*)op = lo;
  *(float4*)(op + 4) = hu;
}

// ---------------- host launch ----------------
extern "C" void kernel_launch(void* const* d_in, const int* in_sizes, int n_in,
                              void* d_out, int out_size, void* d_ws, size_t ws_size,
                              hipStream_t stream)
{
  const float* x  = (const float*)d_in[0];
  const float* wr = (const float*)d_in[1];
  const float* wg = (const float*)d_in[2];
  const float* wu = (const float*)d_in[3];
  const float* wd = (const float*)d_in[4];
  float* out = (float*)d_out;
  char* ws = (char*)d_ws;

  // layout (NEED = 453.8 MB, <= proven-available 454.3 MB):
  // [counts | ids | slotmap | wk | xh(32M) | W1(134M) | H(151M) | W2(134M)]
  // gateup: wgT=W1, wuT=W2.  after gateup: wdT=W1, Y rows<32768 -> W2, rest -> xh.
  const size_t OFF_IDS  = 256;
  const size_t OFF_SLOT = OFF_IDS  + (size_t)NEXP*STRIDE*4;       // 540,928
  const size_t OFF_WK   = OFF_SLOT + (size_t)NTOK*TOPK*4;
  const size_t OFF_XH   = OFF_WK   + (size_t)NTOK*TOPK*4;
  const size_t OFF_W1   = OFF_XH   + (size_t)NTOK*DMODEL*2;
  const size_t OFF_H    = OFF_W1   + (size_t)NEXP*DMODEL*FFN*2;
  const size_t OFF_W2   = OFF_H    + (size_t)MAXT*BM*FFN*2;
  const size_t NEED     = OFF_W2   + (size_t)NEXP*DMODEL*FFN*2;
  if (ws_size < NEED){ k_sentinel<<<1,1,0,stream>>>(out); return; }

  int*      counts  = (int*)ws;
  int*      ids     = (int*)(ws + OFF_IDS);
  int*      slotmap = (int*)(ws + OFF_SLOT);
  float*    wk      = (float*)(ws + OFF_WK);
  _Float16* xh      = (_Float16*)(ws + OFF_XH);
  _Float16* wgT     = (_Float16*)(ws + OFF_W1);
  _Float16* wuT     = (_Float16*)(ws + OFF_W2);
  _Float16* wdT     = wgT;                    // alias: written only after k_gateup
  _Float16* H       = (_Float16*)(ws + OFF_H);
  _Float16* Yw2     = (_Float16*)(ws + OFF_W2);   // alias wuT (dead after gateup)
  _Float16* Yxh     = (_Float16*)(ws + OFF_XH);   // alias xh  (dead after gateup)

  hipMemsetAsync(ws, 0, OFF_SLOT, stream);    // counts + ids

  k_router<<<NTOK, 64, 0, stream>>>(x, wr, counts, ids, slotmap, wk, xh);
  k_transpose<<<dim3(64,64,16), 256, 0, stream>>>(wg, wgT);
  k_transpose<<<dim3(64,64,16), 256, 0, stream>>>(wu, wuT);
  k_gateup<<<MAXT*16, 512, 0, stream>>>(xh, wgT, wuT, counts, ids, H);
  k_transpose<<<dim3(64,64,16), 256, 0, stream>>>(wd, wdT);
  k_down<<<MAXT*8, 512, 0, stream>>>(H, wdT, counts, Yw2, Yxh);
  k_combine<<<NTOK, 256, 0, stream>>>(Yw2, Yxh, counts, slotmap, wk, out);
}